// Round 9
// baseline (195.147 us; speedup 1.0000x reference)
//
#include <hip/hip_runtime.h>
#include <hip/hip_bf16.h>

typedef _Float16 f16;
typedef _Float16 f16x2 __attribute__((ext_vector_type(2)));
typedef _Float16 f16x4 __attribute__((ext_vector_type(4)));
typedef _Float16 f16x8 __attribute__((ext_vector_type(8)));
typedef __fp16 h16x2 __attribute__((ext_vector_type(2)));
typedef float f32x4 __attribute__((ext_vector_type(4)));

// Problem constants
#define NHEADS 6
#define NTOK 256      // tokens per window
#define NWINS 256     // windows (b_)
#define DIM 192
#define HD 32
#define C3 576        // 3*DIM
#define LOG2E 1.4426950408889634f
// Q scale folded with log2e: softmax uses exp2 directly (raw v_exp_f32)
#define SCALE (0.17677669529663687f * LOG2E)

// packed f32x2 -> f16x2 (v_cvt_pkrtz_f16_f32), bit-cast to _Float16 vec type
__device__ inline f16x2 pkrtz(float a, float b) {
  h16x2 r = __builtin_amdgcn_cvt_pkrtz(a, b);
  return __builtin_bit_cast(f16x2, r);
}

// ---------------------------------------------------------------------------
// Kernel 1: CB[mg][h][q][k] = (rpb_table[rpi[q,k],h] + mask[mg][q][k]) * log2e
// r9: output is F32 — attn seeds the QK MFMA C-operand with it directly
// (bias-add becomes free; no f16->f32 cvts, no add loop).
// ---------------------------------------------------------------------------
__global__ __launch_bounds__(256) void prep_cb_kernel(const int* __restrict__ rpi,
                                                      const float* __restrict__ mask,
                                                      const float* __restrict__ rpb,
                                                      float* __restrict__ cb) {
  int idx = blockIdx.x * 256 + threadIdx.x;
  int k = idx & 255;
  int q = (idx >> 8) & 255;
  int t = idx >> 16;       // t = mg*6 + h
  int h = t % 6;
  int mg = t / 6;
  cb[idx] = (rpb[rpi[(q << 8) | k] * 6 + h] + mask[(mg << 16) | (q << 8) | k]) * LOG2E;
}

// ---------------------------------------------------------------------------
// Kernel 2: W (192x192) fp32 -> f16
// ---------------------------------------------------------------------------
__global__ __launch_bounds__(256) void prep_w_kernel(const float* __restrict__ w,
                                                     f16* __restrict__ w16) {
  int i = blockIdx.x * 256 + threadIdx.x;
  if (i < DIM * DIM) w16[i] = (f16)w[i];
}

__device__ inline f16x8 q_to_f16(float4 a, float4 b) {
  f16x2 p0 = pkrtz(a.x * SCALE, a.y * SCALE);
  f16x2 p1 = pkrtz(a.z * SCALE, a.w * SCALE);
  f16x2 p2 = pkrtz(b.x * SCALE, b.y * SCALE);
  f16x2 p3 = pkrtz(b.z * SCALE, b.w * SCALE);
  f16x4 lo = __builtin_shufflevector(p0, p1, 0, 1, 2, 3);
  f16x4 hi = __builtin_shufflevector(p2, p3, 0, 1, 2, 3);
  return __builtin_shufflevector(lo, hi, 0, 1, 2, 3, 4, 5, 6, 7);
}

// ---------------------------------------------------------------------------
// Kernel 3: fused window attention. Block = (b, h). 512 thr = 8 waves.
// Wave w owns q rows [w*32, w*32+32) in 2 chunks of 16; K/V staged ONCE.
//
// r9 structure: 8-wave blocks (33 KB LDS amortized over 8 waves -> up to
// 4 blocks/CU = 32 waves/CU); __launch_bounds__(512,8) (VGPR cap 64);
// bias seeded via MFMA C-operand (f32 CB loads straight into acc);
// NO manual prefetch — TLP at 8 waves/SIMD hides L2/L3 latency.
// Online softmax over 2 k-halves keeps acc[8]=32 regs.
//
// S^T = K . Q^T via mfma_f32_16x16x32_f16; C: q-col=(l&15), key=kt*16+4*(l>>4)+r
// X^T = V^T . P^T via mfma_f32_16x16x16f16: P^T C-layout == B-operand layout.
// ---------------------------------------------------------------------------
__global__ __launch_bounds__(512, 8) void attn_kernel(const float* __restrict__ qkv,
                                                      const float* __restrict__ cb,
                                                      f16* __restrict__ x16) {
  const int idx = blockIdx.x;
  const int b = idx & 255;
  const int h = idx >> 8;
  const int tid = threadIdx.x;
  const int lane = tid & 63;
  const int wave = tid >> 6;
  const int g = lane >> 4;
  const int r16 = lane & 15;

  __shared__ f16 Klin[16 * 64 * 8];   // frag-linear (XOR-swizzled), 16 KB
  __shared__ f16 VT[32][264];         // [d][key^((d&7)<<2)] padded

  // ---- stage K (waves 0-3) / V (waves 4-7); 2 batches of 4 float4 ----
  {
    const int t = tid & 255;
    const int srow = t >> 3;   // 0..31
    const int part = t & 7;    // which 16B of the 128B row segment
    const bool isK = tid < 256;            // wave-uniform
    const float* base = qkv + (size_t)(b * NTOK + srow) * C3 + DIM + (isK ? 0 : DIM)
                        + h * HD + part * 4;
    const int gg = part >> 1;
    const int half = part & 1;
    const int d0 = part * 4;
#pragma unroll
    for (int batch = 0; batch < 2; ++batch) {
      float4 v4[4];
#pragma unroll
      for (int rg = 0; rg < 4; ++rg)
        v4[rg] = *(const float4*)(base + (size_t)((batch * 4 + rg) * 32) * C3);
#pragma unroll
      for (int rg = 0; rg < 4; ++rg) {
        const int row = (batch * 4 + rg) * 32 + srow;
        if (isK) {
          const int slot = ((row >> 4) * 64) + gg * 16 + ((row & 15) ^ (gg << 2));
          f16x2 k01 = pkrtz(v4[rg].x, v4[rg].y);
          f16x2 k23 = pkrtz(v4[rg].z, v4[rg].w);
          *((f16x4*)&Klin[slot * 8 + half * 4]) =
              __builtin_shufflevector(k01, k23, 0, 1, 2, 3);
        } else {
          VT[d0 + 0][row ^ (((d0 + 0) & 7) << 2)] = (f16)v4[rg].x;
          VT[d0 + 1][row ^ (((d0 + 1) & 7) << 2)] = (f16)v4[rg].y;
          VT[d0 + 2][row ^ (((d0 + 2) & 7) << 2)] = (f16)v4[rg].z;
          VT[d0 + 3][row ^ (((d0 + 3) & 7) << 2)] = (f16)v4[rg].w;
        }
      }
    }
  }
  __syncthreads();

  const int qbase = wave * 32;
  const float* cbb = cb + (((size_t)((b & 15) * 6 + h)) << 16);
  // swizzled Klin read offset for this lane
  const int krd = (lane & 48) + ((lane & 15) ^ ((lane >> 2) & 12));

#pragma unroll
  for (int c = 0; c < 2; ++c) {
    const int qrow = qbase + c * 16 + r16;
    const float* qp = qkv + (size_t)(b * NTOK + qrow) * C3 + h * HD + g * 8;
    f16x8 qf = q_to_f16(((const float4*)qp)[0], ((const float4*)qp)[1]);
    const float* cbq = cbb + ((size_t)qrow << 8) + g * 4;

    // ================= phase A: keys 0..127 =================
    f32x4 acc[8];
#pragma unroll
    for (int kt = 0; kt < 8; ++kt)
      acc[kt] = *((const f32x4*)(cbq + kt * 16));       // bias seeds C
#pragma unroll
    for (int kt = 0; kt < 8; ++kt) {
      f16x8 af = *((const f16x8*)&Klin[(kt * 64 + krd) * 8]);
      acc[kt] = __builtin_amdgcn_mfma_f32_16x16x32_f16(af, qf, acc[kt], 0, 0, 0);
    }

    float m0 = fmaxf(fmaxf(acc[0][0], acc[1][0]), fmaxf(acc[2][0], acc[3][0]));
    float m1 = fmaxf(fmaxf(acc[0][1], acc[1][1]), fmaxf(acc[2][1], acc[3][1]));
    float m2 = fmaxf(fmaxf(acc[0][2], acc[1][2]), fmaxf(acc[2][2], acc[3][2]));
    float m3 = fmaxf(fmaxf(acc[0][3], acc[1][3]), fmaxf(acc[2][3], acc[3][3]));
#pragma unroll
    for (int kt = 4; kt < 8; ++kt) {
      m0 = fmaxf(m0, acc[kt][0]); m1 = fmaxf(m1, acc[kt][1]);
      m2 = fmaxf(m2, acc[kt][2]); m3 = fmaxf(m3, acc[kt][3]);
    }
    float mA = fmaxf(fmaxf(m0, m1), fmaxf(m2, m3));
    mA = fmaxf(mA, __shfl_xor(mA, 16));
    mA = fmaxf(mA, __shfl_xor(mA, 32));

    float s0 = 0.f, s1 = 0.f, s2 = 0.f, s3 = 0.f;
#pragma unroll
    for (int kt = 0; kt < 8; ++kt) {
      float p0 = __builtin_amdgcn_exp2f(acc[kt][0] - mA);
      float p1 = __builtin_amdgcn_exp2f(acc[kt][1] - mA);
      float p2 = __builtin_amdgcn_exp2f(acc[kt][2] - mA);
      float p3 = __builtin_amdgcn_exp2f(acc[kt][3] - mA);
      acc[kt][0] = p0; acc[kt][1] = p1; acc[kt][2] = p2; acc[kt][3] = p3;
      s0 += p0; s1 += p1; s2 += p2; s3 += p3;
    }
    float sA = (s0 + s1) + (s2 + s3);

    // PV phase A
    f32x4 xacc[2];
    xacc[0][0] = 0.f; xacc[0][1] = 0.f; xacc[0][2] = 0.f; xacc[0][3] = 0.f;
    xacc[1][0] = 0.f; xacc[1][1] = 0.f; xacc[1][2] = 0.f; xacc[1][3] = 0.f;
#pragma unroll
    for (int kt = 0; kt < 8; ++kt) {
      f16x2 p01 = pkrtz(acc[kt][0], acc[kt][1]);
      f16x2 p23 = pkrtz(acc[kt][2], acc[kt][3]);
      f16x4 pf = __builtin_shufflevector(p01, p23, 0, 1, 2, 3);
#pragma unroll
      for (int dt = 0; dt < 2; ++dt) {
        const int col = (kt * 16 + g * 4) ^ ((r16 & 7) << 2);
        f16x4 vf = *((const f16x4*)&VT[dt * 16 + r16][col]);
        xacc[dt] = __builtin_amdgcn_mfma_f32_16x16x16f16(vf, pf, xacc[dt], 0, 0, 0);
      }
    }

    // ================= phase B: keys 128..255 =================
#pragma unroll
    for (int kt = 0; kt < 8; ++kt)
      acc[kt] = *((const f32x4*)(cbq + 128 + kt * 16));  // bias seeds C
#pragma unroll
    for (int kt = 0; kt < 8; ++kt) {
      f16x8 af = *((const f16x8*)&Klin[((kt + 8) * 64 + krd) * 8]);
      acc[kt] = __builtin_amdgcn_mfma_f32_16x16x32_f16(af, qf, acc[kt], 0, 0, 0);
    }

    m0 = fmaxf(fmaxf(acc[0][0], acc[1][0]), fmaxf(acc[2][0], acc[3][0]));
    m1 = fmaxf(fmaxf(acc[0][1], acc[1][1]), fmaxf(acc[2][1], acc[3][1]));
    m2 = fmaxf(fmaxf(acc[0][2], acc[1][2]), fmaxf(acc[2][2], acc[3][2]));
    m3 = fmaxf(fmaxf(acc[0][3], acc[1][3]), fmaxf(acc[2][3], acc[3][3]));
#pragma unroll
    for (int kt = 4; kt < 8; ++kt) {
      m0 = fmaxf(m0, acc[kt][0]); m1 = fmaxf(m1, acc[kt][1]);
      m2 = fmaxf(m2, acc[kt][2]); m3 = fmaxf(m3, acc[kt][3]);
    }
    float mB = fmaxf(fmaxf(m0, m1), fmaxf(m2, m3));
    mB = fmaxf(mB, __shfl_xor(mB, 16));
    mB = fmaxf(mB, __shfl_xor(mB, 32));

    const float m = fmaxf(mA, mB);
    const float scA = __builtin_amdgcn_exp2f(mA - m);

    s0 = 0.f; s1 = 0.f; s2 = 0.f; s3 = 0.f;
#pragma unroll
    for (int kt = 0; kt < 8; ++kt) {
      float p0 = __builtin_amdgcn_exp2f(acc[kt][0] - m);
      float p1 = __builtin_amdgcn_exp2f(acc[kt][1] - m);
      float p2 = __builtin_amdgcn_exp2f(acc[kt][2] - m);
      float p3 = __builtin_amdgcn_exp2f(acc[kt][3] - m);
      acc[kt][0] = p0; acc[kt][1] = p1; acc[kt][2] = p2; acc[kt][3] = p3;
      s0 += p0; s1 += p1; s2 += p2; s3 += p3;
    }
    // per-lane partial denominator; reduce across the 4-lane q-row group
    float s = sA * scA + (s0 + s1) + (s2 + s3);
    s += __shfl_xor(s, 16);
    s += __shfl_xor(s, 32);
    const float rinv = 1.0f / s;

    // rescale phase-A PV then accumulate phase B
    xacc[0][0] *= scA; xacc[0][1] *= scA; xacc[0][2] *= scA; xacc[0][3] *= scA;
    xacc[1][0] *= scA; xacc[1][1] *= scA; xacc[1][2] *= scA; xacc[1][3] *= scA;
#pragma unroll
    for (int kt = 0; kt < 8; ++kt) {
      f16x2 p01 = pkrtz(acc[kt][0], acc[kt][1]);
      f16x2 p23 = pkrtz(acc[kt][2], acc[kt][3]);
      f16x4 pf = __builtin_shufflevector(p01, p23, 0, 1, 2, 3);
#pragma unroll
      for (int dt = 0; dt < 2; ++dt) {
        const int col = ((kt + 8) * 16 + g * 4) ^ ((r16 & 7) << 2);
        f16x4 vf = *((const f16x4*)&VT[dt * 16 + r16][col]);
        xacc[dt] = __builtin_amdgcn_mfma_f32_16x16x16f16(vf, pf, xacc[dt], 0, 0, 0);
      }
    }

    // write x (f16) [b][token][192], normalized
    f16* xp = x16 + (size_t)(b * NTOK + qrow) * DIM + h * HD;
#pragma unroll
    for (int dt = 0; dt < 2; ++dt) {
      f16x2 o01 = pkrtz(xacc[dt][0] * rinv, xacc[dt][1] * rinv);
      f16x2 o23 = pkrtz(xacc[dt][2] * rinv, xacc[dt][3] * rinv);
      *((f16x4*)(xp + dt * 16 + g * 4)) = __builtin_shufflevector(o01, o23, 0, 1, 2, 3);
    }
  }
}

// ---------------------------------------------------------------------------
// Kernel 4: out[m][j] = sum_c X16[m][c] * W16[j][c] + pb[j]
// ---------------------------------------------------------------------------
__global__ __launch_bounds__(256) void proj_kernel(const f16* __restrict__ x16,
                                                   const f16* __restrict__ w16,
                                                   const float* __restrict__ pb,
                                                   float* __restrict__ out) {
  const int lane = threadIdx.x & 63;
  const int wave = threadIdx.x >> 6;
  const int g = lane >> 4;
  const int r16 = lane & 15;
  const int m0 = blockIdx.x * 64 + wave * 16;

  f32x4 acc[12];
#pragma unroll
  for (int jt = 0; jt < 12; ++jt) {
    acc[jt][0] = 0.f; acc[jt][1] = 0.f; acc[jt][2] = 0.f; acc[jt][3] = 0.f;
  }
#pragma unroll
  for (int cc = 0; cc < 6; ++cc) {
    f16x8 af = *((const f16x8*)(x16 + (size_t)(m0 + r16) * DIM + cc * 32 + g * 8));
#pragma unroll
    for (int jt = 0; jt < 12; ++jt) {
      f16x8 bf = *((const f16x8*)(w16 + (size_t)(jt * 16 + r16) * DIM + cc * 32 + g * 8));
      acc[jt] = __builtin_amdgcn_mfma_f32_16x16x32_f16(af, bf, acc[jt], 0, 0, 0);
    }
  }
#pragma unroll
  for (int jt = 0; jt < 12; ++jt) {
    int j = jt * 16 + r16;
    float bias = pb[j];
#pragma unroll
    for (int r = 0; r < 4; ++r) {
      out[(size_t)(m0 + g * 4 + r) * DIM + j] = acc[jt][r] + bias;
    }
  }
}

// ---------------------------------------------------------------------------
extern "C" void kernel_launch(void* const* d_in, const int* in_sizes, int n_in,
                              void* d_out, int out_size, void* d_ws, size_t ws_size,
                              hipStream_t stream) {
  const float* qkv  = (const float*)d_in[0];
  const int*   rpi  = (const int*)d_in[1];
  const float* mask = (const float*)d_in[2];
  const float* rpb  = (const float*)d_in[3];
  const float* pw   = (const float*)d_in[4];
  const float* pbv  = (const float*)d_in[5];
  float* out = (float*)d_out;

  char* ws = (char*)d_ws;
  float* cb = (float*)ws;                            // 16*6*256*256*4 = 25,165,824 B
  f16* x16  = (f16*)(ws + 25165824);                 // 25,165,824 B
  f16* w16  = (f16*)(ws + 25165824 + 25165824);      // 73,728 B

  prep_cb_kernel<<<24576, 256, 0, stream>>>(rpi, mask, rpb, cb);
  prep_w_kernel<<<144, 256, 0, stream>>>(pw, w16);
  attn_kernel<<<1536, 512, 0, stream>>>(qkv, cb, x16);
  proj_kernel<<<1024, 256, 0, stream>>>(x16, w16, pbv, out);
}

// Round 10
// 122.941 us; speedup vs baseline: 1.5873x; 1.5873x over previous
//
#include <hip/hip_runtime.h>
#include <hip/hip_bf16.h>

typedef _Float16 f16;
typedef _Float16 f16x2 __attribute__((ext_vector_type(2)));
typedef _Float16 f16x4 __attribute__((ext_vector_type(4)));
typedef _Float16 f16x8 __attribute__((ext_vector_type(8)));
typedef __fp16 h16x2 __attribute__((ext_vector_type(2)));
typedef float f32x4 __attribute__((ext_vector_type(4)));

// Problem constants
#define NHEADS 6
#define NTOK 256      // tokens per window
#define NWINS 256     // windows (b_)
#define DIM 192
#define HD 32
#define C3 576        // 3*DIM
#define LOG2E 1.4426950408889634f
// Q scale folded with log2e: softmax uses exp2 directly (raw v_exp_f32)
#define SCALE (0.17677669529663687f * LOG2E)

// packed f32x2 -> f16x2 (v_cvt_pkrtz_f16_f32), bit-cast to _Float16 vec type
__device__ inline f16x2 pkrtz(float a, float b) {
  h16x2 r = __builtin_amdgcn_cvt_pkrtz(a, b);
  return __builtin_bit_cast(f16x2, r);
}

// ---------------------------------------------------------------------------
// Kernel 1: CB[mg][h][q][k] = (rpb_table[rpi[q,k],h] + mask[mg][q][k]) * log2e
// F32 output — attn seeds the QK MFMA C-operand with it directly.
// ---------------------------------------------------------------------------
__global__ __launch_bounds__(256) void prep_cb_kernel(const int* __restrict__ rpi,
                                                      const float* __restrict__ mask,
                                                      const float* __restrict__ rpb,
                                                      float* __restrict__ cb) {
  int idx = blockIdx.x * 256 + threadIdx.x;
  int k = idx & 255;
  int q = (idx >> 8) & 255;
  int t = idx >> 16;       // t = mg*6 + h
  int h = t % 6;
  int mg = t / 6;
  cb[idx] = (rpb[rpi[(q << 8) | k] * 6 + h] + mask[(mg << 16) | (q << 8) | k]) * LOG2E;
}

// ---------------------------------------------------------------------------
// Kernel 2: W (192x192) fp32 -> f16
// ---------------------------------------------------------------------------
__global__ __launch_bounds__(256) void prep_w_kernel(const float* __restrict__ w,
                                                     f16* __restrict__ w16) {
  int i = blockIdx.x * 256 + threadIdx.x;
  if (i < DIM * DIM) w16[i] = (f16)w[i];
}

__device__ inline f16x8 q_to_f16(float4 a, float4 b) {
  f16x2 p0 = pkrtz(a.x * SCALE, a.y * SCALE);
  f16x2 p1 = pkrtz(a.z * SCALE, a.w * SCALE);
  f16x2 p2 = pkrtz(b.x * SCALE, b.y * SCALE);
  f16x2 p3 = pkrtz(b.z * SCALE, b.w * SCALE);
  f16x4 lo = __builtin_shufflevector(p0, p1, 0, 1, 2, 3);
  f16x4 hi = __builtin_shufflevector(p2, p3, 0, 1, 2, 3);
  return __builtin_shufflevector(lo, hi, 0, 1, 2, 3, 4, 5, 6, 7);
}

// ---------------------------------------------------------------------------
// Kernel 3: fused window attention. Block = (b, h). 512 thr = 8 waves.
// Wave w owns q rows [w*32, w*32+32) in 2 chunks of 16; K/V staged ONCE.
//
// r10: __launch_bounds__(512,4) — 128 unified regs/wave. r9's (512,8) capped
// at 64 and spilled 210 MB of scratch (the unified VGPR/AGPR file is 512
// regs/SIMD; 8 waves -> 64/wave). Peak live here ~100 regs -> no spill at 128.
// PV accumulation split into 2 chains per dt (halves the 16-deep dependent
// MFMA chain). Bias seeds MFMA C-operand; no manual prefetch (TLP covers).
//
// S^T = K . Q^T via mfma_f32_16x16x32_f16; C: q-col=(l&15), key=kt*16+4*(l>>4)+r
// X^T = V^T . P^T via mfma_f32_16x16x16f16: P^T C-layout == B-operand layout.
// ---------------------------------------------------------------------------
__global__ __launch_bounds__(512, 4) void attn_kernel(const float* __restrict__ qkv,
                                                      const float* __restrict__ cb,
                                                      f16* __restrict__ x16) {
  const int idx = blockIdx.x;
  const int b = idx & 255;
  const int h = idx >> 8;
  const int tid = threadIdx.x;
  const int lane = tid & 63;
  const int wave = tid >> 6;
  const int g = lane >> 4;
  const int r16 = lane & 15;

  __shared__ f16 Klin[16 * 64 * 8];   // frag-linear (XOR-swizzled), 16 KB
  __shared__ f16 VT[32][264];         // [d][key^((d&7)<<2)] padded

  // ---- stage K (waves 0-3) / V (waves 4-7); 2 batches of 4 float4 ----
  {
    const int t = tid & 255;
    const int srow = t >> 3;   // 0..31
    const int part = t & 7;    // which 16B of the 128B row segment
    const bool isK = tid < 256;            // wave-uniform
    const float* base = qkv + (size_t)(b * NTOK + srow) * C3 + DIM + (isK ? 0 : DIM)
                        + h * HD + part * 4;
    const int gg = part >> 1;
    const int half = part & 1;
    const int d0 = part * 4;
#pragma unroll
    for (int batch = 0; batch < 2; ++batch) {
      float4 v4[4];
#pragma unroll
      for (int rg = 0; rg < 4; ++rg)
        v4[rg] = *(const float4*)(base + (size_t)((batch * 4 + rg) * 32) * C3);
#pragma unroll
      for (int rg = 0; rg < 4; ++rg) {
        const int row = (batch * 4 + rg) * 32 + srow;
        if (isK) {
          const int slot = ((row >> 4) * 64) + gg * 16 + ((row & 15) ^ (gg << 2));
          f16x2 k01 = pkrtz(v4[rg].x, v4[rg].y);
          f16x2 k23 = pkrtz(v4[rg].z, v4[rg].w);
          *((f16x4*)&Klin[slot * 8 + half * 4]) =
              __builtin_shufflevector(k01, k23, 0, 1, 2, 3);
        } else {
          VT[d0 + 0][row ^ (((d0 + 0) & 7) << 2)] = (f16)v4[rg].x;
          VT[d0 + 1][row ^ (((d0 + 1) & 7) << 2)] = (f16)v4[rg].y;
          VT[d0 + 2][row ^ (((d0 + 2) & 7) << 2)] = (f16)v4[rg].z;
          VT[d0 + 3][row ^ (((d0 + 3) & 7) << 2)] = (f16)v4[rg].w;
        }
      }
    }
  }
  __syncthreads();

  const int qbase = wave * 32;
  const float* cbb = cb + (((size_t)((b & 15) * 6 + h)) << 16);
  // swizzled Klin read offset for this lane
  const int krd = (lane & 48) + ((lane & 15) ^ ((lane >> 2) & 12));

#pragma unroll
  for (int c = 0; c < 2; ++c) {
    const int qrow = qbase + c * 16 + r16;
    const float* qp = qkv + (size_t)(b * NTOK + qrow) * C3 + h * HD + g * 8;
    f16x8 qf = q_to_f16(((const float4*)qp)[0], ((const float4*)qp)[1]);
    const float* cbq = cbb + ((size_t)qrow << 8) + g * 4;

    // ================= phase A: keys 0..127 =================
    f32x4 acc[8];
#pragma unroll
    for (int kt = 0; kt < 8; ++kt)
      acc[kt] = *((const f32x4*)(cbq + kt * 16));       // bias seeds C
#pragma unroll
    for (int kt = 0; kt < 8; ++kt) {
      f16x8 af = *((const f16x8*)&Klin[(kt * 64 + krd) * 8]);
      acc[kt] = __builtin_amdgcn_mfma_f32_16x16x32_f16(af, qf, acc[kt], 0, 0, 0);
    }

    float m0 = fmaxf(fmaxf(acc[0][0], acc[1][0]), fmaxf(acc[2][0], acc[3][0]));
    float m1 = fmaxf(fmaxf(acc[0][1], acc[1][1]), fmaxf(acc[2][1], acc[3][1]));
    float m2 = fmaxf(fmaxf(acc[0][2], acc[1][2]), fmaxf(acc[2][2], acc[3][2]));
    float m3 = fmaxf(fmaxf(acc[0][3], acc[1][3]), fmaxf(acc[2][3], acc[3][3]));
#pragma unroll
    for (int kt = 4; kt < 8; ++kt) {
      m0 = fmaxf(m0, acc[kt][0]); m1 = fmaxf(m1, acc[kt][1]);
      m2 = fmaxf(m2, acc[kt][2]); m3 = fmaxf(m3, acc[kt][3]);
    }
    float mA = fmaxf(fmaxf(m0, m1), fmaxf(m2, m3));
    mA = fmaxf(mA, __shfl_xor(mA, 16));
    mA = fmaxf(mA, __shfl_xor(mA, 32));

    float s0 = 0.f, s1 = 0.f, s2 = 0.f, s3 = 0.f;
#pragma unroll
    for (int kt = 0; kt < 8; ++kt) {
      float p0 = __builtin_amdgcn_exp2f(acc[kt][0] - mA);
      float p1 = __builtin_amdgcn_exp2f(acc[kt][1] - mA);
      float p2 = __builtin_amdgcn_exp2f(acc[kt][2] - mA);
      float p3 = __builtin_amdgcn_exp2f(acc[kt][3] - mA);
      acc[kt][0] = p0; acc[kt][1] = p1; acc[kt][2] = p2; acc[kt][3] = p3;
      s0 += p0; s1 += p1; s2 += p2; s3 += p3;
    }
    float sA = (s0 + s1) + (s2 + s3);

    // PV phase A — 2 chains per dt (xa0/xa1) to halve the MFMA dep chain
    f32x4 xa0[2], xa1[2];
#pragma unroll
    for (int dt = 0; dt < 2; ++dt) {
      xa0[dt][0] = 0.f; xa0[dt][1] = 0.f; xa0[dt][2] = 0.f; xa0[dt][3] = 0.f;
      xa1[dt][0] = 0.f; xa1[dt][1] = 0.f; xa1[dt][2] = 0.f; xa1[dt][3] = 0.f;
    }
#pragma unroll
    for (int kt = 0; kt < 8; ++kt) {
      f16x2 p01 = pkrtz(acc[kt][0], acc[kt][1]);
      f16x2 p23 = pkrtz(acc[kt][2], acc[kt][3]);
      f16x4 pf = __builtin_shufflevector(p01, p23, 0, 1, 2, 3);
#pragma unroll
      for (int dt = 0; dt < 2; ++dt) {
        const int col = (kt * 16 + g * 4) ^ ((r16 & 7) << 2);
        f16x4 vf = *((const f16x4*)&VT[dt * 16 + r16][col]);
        if (kt < 4)
          xa0[dt] = __builtin_amdgcn_mfma_f32_16x16x16f16(vf, pf, xa0[dt], 0, 0, 0);
        else
          xa1[dt] = __builtin_amdgcn_mfma_f32_16x16x16f16(vf, pf, xa1[dt], 0, 0, 0);
      }
    }

    // ================= phase B: keys 128..255 =================
#pragma unroll
    for (int kt = 0; kt < 8; ++kt)
      acc[kt] = *((const f32x4*)(cbq + 128 + kt * 16));  // bias seeds C
#pragma unroll
    for (int kt = 0; kt < 8; ++kt) {
      f16x8 af = *((const f16x8*)&Klin[((kt + 8) * 64 + krd) * 8]);
      acc[kt] = __builtin_amdgcn_mfma_f32_16x16x32_f16(af, qf, acc[kt], 0, 0, 0);
    }

    m0 = fmaxf(fmaxf(acc[0][0], acc[1][0]), fmaxf(acc[2][0], acc[3][0]));
    m1 = fmaxf(fmaxf(acc[0][1], acc[1][1]), fmaxf(acc[2][1], acc[3][1]));
    m2 = fmaxf(fmaxf(acc[0][2], acc[1][2]), fmaxf(acc[2][2], acc[3][2]));
    m3 = fmaxf(fmaxf(acc[0][3], acc[1][3]), fmaxf(acc[2][3], acc[3][3]));
#pragma unroll
    for (int kt = 4; kt < 8; ++kt) {
      m0 = fmaxf(m0, acc[kt][0]); m1 = fmaxf(m1, acc[kt][1]);
      m2 = fmaxf(m2, acc[kt][2]); m3 = fmaxf(m3, acc[kt][3]);
    }
    float mB = fmaxf(fmaxf(m0, m1), fmaxf(m2, m3));
    mB = fmaxf(mB, __shfl_xor(mB, 16));
    mB = fmaxf(mB, __shfl_xor(mB, 32));

    const float m = fmaxf(mA, mB);
    const float scA = __builtin_amdgcn_exp2f(mA - m);

    s0 = 0.f; s1 = 0.f; s2 = 0.f; s3 = 0.f;
#pragma unroll
    for (int kt = 0; kt < 8; ++kt) {
      float p0 = __builtin_amdgcn_exp2f(acc[kt][0] - m);
      float p1 = __builtin_amdgcn_exp2f(acc[kt][1] - m);
      float p2 = __builtin_amdgcn_exp2f(acc[kt][2] - m);
      float p3 = __builtin_amdgcn_exp2f(acc[kt][3] - m);
      acc[kt][0] = p0; acc[kt][1] = p1; acc[kt][2] = p2; acc[kt][3] = p3;
      s0 += p0; s1 += p1; s2 += p2; s3 += p3;
    }
    // per-lane partial denominator; reduce across the 4-lane q-row group
    float s = sA * scA + (s0 + s1) + (s2 + s3);
    s += __shfl_xor(s, 16);
    s += __shfl_xor(s, 32);
    const float rinv = 1.0f / s;

    // rescale phase-A PV then accumulate phase B
#pragma unroll
    for (int dt = 0; dt < 2; ++dt) {
      xa0[dt][0] *= scA; xa0[dt][1] *= scA; xa0[dt][2] *= scA; xa0[dt][3] *= scA;
      xa1[dt][0] *= scA; xa1[dt][1] *= scA; xa1[dt][2] *= scA; xa1[dt][3] *= scA;
    }
#pragma unroll
    for (int kt = 0; kt < 8; ++kt) {
      f16x2 p01 = pkrtz(acc[kt][0], acc[kt][1]);
      f16x2 p23 = pkrtz(acc[kt][2], acc[kt][3]);
      f16x4 pf = __builtin_shufflevector(p01, p23, 0, 1, 2, 3);
#pragma unroll
      for (int dt = 0; dt < 2; ++dt) {
        const int col = ((kt + 8) * 16 + g * 4) ^ ((r16 & 7) << 2);
        f16x4 vf = *((const f16x4*)&VT[dt * 16 + r16][col]);
        if (kt < 4)
          xa0[dt] = __builtin_amdgcn_mfma_f32_16x16x16f16(vf, pf, xa0[dt], 0, 0, 0);
        else
          xa1[dt] = __builtin_amdgcn_mfma_f32_16x16x16f16(vf, pf, xa1[dt], 0, 0, 0);
      }
    }

    // write x (f16) [b][token][192], normalized
    f16* xp = x16 + (size_t)(b * NTOK + qrow) * DIM + h * HD;
#pragma unroll
    for (int dt = 0; dt < 2; ++dt) {
      f16x2 o01 = pkrtz((xa0[dt][0] + xa1[dt][0]) * rinv,
                        (xa0[dt][1] + xa1[dt][1]) * rinv);
      f16x2 o23 = pkrtz((xa0[dt][2] + xa1[dt][2]) * rinv,
                        (xa0[dt][3] + xa1[dt][3]) * rinv);
      *((f16x4*)(xp + dt * 16 + g * 4)) = __builtin_shufflevector(o01, o23, 0, 1, 2, 3);
    }
  }
}

// ---------------------------------------------------------------------------
// Kernel 4: out[m][j] = sum_c X16[m][c] * W16[j][c] + pb[j]
// ---------------------------------------------------------------------------
__global__ __launch_bounds__(256) void proj_kernel(const f16* __restrict__ x16,
                                                   const f16* __restrict__ w16,
                                                   const float* __restrict__ pb,
                                                   float* __restrict__ out) {
  const int lane = threadIdx.x & 63;
  const int wave = threadIdx.x >> 6;
  const int g = lane >> 4;
  const int r16 = lane & 15;
  const int m0 = blockIdx.x * 64 + wave * 16;

  f32x4 acc[12];
#pragma unroll
  for (int jt = 0; jt < 12; ++jt) {
    acc[jt][0] = 0.f; acc[jt][1] = 0.f; acc[jt][2] = 0.f; acc[jt][3] = 0.f;
  }
#pragma unroll
  for (int cc = 0; cc < 6; ++cc) {
    f16x8 af = *((const f16x8*)(x16 + (size_t)(m0 + r16) * DIM + cc * 32 + g * 8));
#pragma unroll
    for (int jt = 0; jt < 12; ++jt) {
      f16x8 bf = *((const f16x8*)(w16 + (size_t)(jt * 16 + r16) * DIM + cc * 32 + g * 8));
      acc[jt] = __builtin_amdgcn_mfma_f32_16x16x32_f16(af, bf, acc[jt], 0, 0, 0);
    }
  }
#pragma unroll
  for (int jt = 0; jt < 12; ++jt) {
    int j = jt * 16 + r16;
    float bias = pb[j];
#pragma unroll
    for (int r = 0; r < 4; ++r) {
      out[(size_t)(m0 + g * 4 + r) * DIM + j] = acc[jt][r] + bias;
    }
  }
}

// ---------------------------------------------------------------------------
extern "C" void kernel_launch(void* const* d_in, const int* in_sizes, int n_in,
                              void* d_out, int out_size, void* d_ws, size_t ws_size,
                              hipStream_t stream) {
  const float* qkv  = (const float*)d_in[0];
  const int*   rpi  = (const int*)d_in[1];
  const float* mask = (const float*)d_in[2];
  const float* rpb  = (const float*)d_in[3];
  const float* pw   = (const float*)d_in[4];
  const float* pbv  = (const float*)d_in[5];
  float* out = (float*)d_out;

  char* ws = (char*)d_ws;
  float* cb = (float*)ws;                            // 16*6*256*256*4 = 25,165,824 B
  f16* x16  = (f16*)(ws + 25165824);                 // 25,165,824 B
  f16* w16  = (f16*)(ws + 25165824 + 25165824);      // 73,728 B

  prep_cb_kernel<<<24576, 256, 0, stream>>>(rpi, mask, rpb, cb);
  prep_w_kernel<<<144, 256, 0, stream>>>(pw, w16);
  attn_kernel<<<1536, 512, 0, stream>>>(qkv, cb, x16);
  proj_kernel<<<1024, 256, 0, stream>>>(x16, w16, pbv, out);
}